// Round 8
// baseline (802.605 us; speedup 1.0000x reference)
//
#include <hip/hip_runtime.h>
#include <math.h>

// Problem constants
constexpr int NB = 32, ND = 512, NHID = 512, NSTEPS = 31;
constexpr int NC5 = 2560;          // 5H
constexpr int BH = NB * NHID;      // 16384
constexpr int SLOT_Z = 32;         // zero h/c slot
constexpr int SLOT_DUMMY = 126;    // dummy candidate (never read)
constexpr int NSLOTS = 128;        // 0..31 leaves, 32 zero, 33..63 step0 cands,
                                   // 64+2s/65+2s cands born at step s+1, 126 dummy
constexpr int NBLK = 128;          // unit blocks (4 hidden units each), all redundant owners

constexpr float INV2048 = 1.f / 2048.f;

typedef _Float16 half8  __attribute__((ext_vector_type(8)));
typedef _Float16 half4  __attribute__((ext_vector_type(4)));
typedef float    f32x16 __attribute__((ext_vector_type(16)));
typedef unsigned long long u64;

// ---------------- workspace layout (float offsets) ----------------
constexpr size_t OFF_WTH  = 0;                                     // W^T hi [2560][1024]
constexpr size_t OFF_WTL  = OFF_WTH + (size_t)NC5 * 1024 / 2;
constexpr size_t OFF_WPH  = OFF_WTL + (size_t)NC5 * 1024 / 2;      // permuted [128][32][1024]
constexpr size_t OFF_WPL  = OFF_WPH + (size_t)128 * 32 * 1024 / 2;
constexpr size_t OFF_HHI  = OFF_WPL + (size_t)128 * 32 * 1024 / 2; // [128][32][512] halves
constexpr size_t OFF_HLO  = OFF_HHI + (size_t)NSLOTS * 32 * 512 / 2;
constexpr size_t OFF_HF32 = OFF_HLO + (size_t)NSLOTS * 32 * 512 / 2; // [128][32][512] f32
constexpr size_t OFF_CF32 = OFF_HF32 + (size_t)NSLOTS * 32 * 512;    // [128][32][512] f32
constexpr size_t OFF_CST  = OFF_CF32 + (size_t)NSLOTS * 32 * 512;    // leaf c [32][32][512]
constexpr size_t OFF_LPART= OFF_CST + (size_t)32 * 32 * 512;       // [128][32][128] f32
constexpr size_t OFF_SEL  = OFF_LPART + (size_t)NSLOTS * 32 * 128; // int [31][32]
constexpr size_t OFF_IREG = OFF_SEL + 1024;                        // gd[128]

__device__ __forceinline__ float sigf(float x) { return 1.f / (1.f + expf(-x)); }

// device-scope (L2-bypassing) helpers
__device__ __forceinline__ int ld_sc(const int* p) {
    return __hip_atomic_load(p, __ATOMIC_RELAXED, __HIP_MEMORY_SCOPE_AGENT);
}
__device__ __forceinline__ void st_sc64(void* p, u64 v) {
    __hip_atomic_store((u64*)p, v, __ATOMIC_RELAXED, __HIP_MEMORY_SCOPE_AGENT);
}
__device__ __forceinline__ void st_sc32f(void* p, float v) {
    __hip_atomic_store((int*)p, __float_as_int(v), __ATOMIC_RELAXED, __HIP_MEMORY_SCOPE_AGENT);
}
// entry pack: b[0:5) cand[5:12) l[12:19) r[19:26)
__device__ __forceinline__ unsigned pack_e(int b, int cand, int l, int r) {
    return (unsigned)b | ((unsigned)cand << 5) | ((unsigned)l << 12) | ((unsigned)r << 19);
}

// ---------------- init: counters, zero h slot ----------------
__global__ __launch_bounds__(256) void init_kernel(
    int* __restrict__ ireg, _Float16* __restrict__ hHi, _Float16* __restrict__ hLo)
{
    const int tid = threadIdx.x;
    if (tid < 128) ireg[tid] = 0;
    const size_t zb = (size_t)SLOT_Z * 32 * 512;
    for (int i = tid; i < 32 * 512; i += 256) {
        hHi[zb + i] = (_Float16)0.f;
        hLo[zb + i] = (_Float16)0.f;
    }
}

// ---------------- W_comp -> transposed split fp16 planes ----------------
__global__ __launch_bounds__(256) void wsplit_kernel(
    const float* __restrict__ W, _Float16* __restrict__ Wth, _Float16* __restrict__ Wtl)
{
    __shared__ float t[32][33];
    const int n0 = blockIdx.x * 32, k0 = blockIdx.y * 32;
    const int tid = threadIdx.x;
    const int c = tid & 31, r8 = tid >> 5;
#pragma unroll
    for (int p = 0; p < 4; ++p) {
        int r = p * 8 + r8;
        t[r][c] = W[(size_t)(k0 + r) * NC5 + n0 + c];
    }
    __syncthreads();
    const int nl = tid >> 3, k4 = (tid & 7) * 4;
    half4 vh, vl;
#pragma unroll
    for (int i = 0; i < 4; ++i) {
        float v = t[k4 + i][nl];
        _Float16 hh = (_Float16)v;
        vh[i] = hh;
        vl[i] = (_Float16)((v - (float)hh) * 2048.f);
    }
    size_t o = (size_t)(n0 + nl) * 1024 + k0 + k4;
    *(half4*)&Wth[o] = vh;
    *(half4*)&Wtl[o] = vl;
}

// ---------------- permute W^T into per-block unit-gate panels ----------------
__global__ __launch_bounds__(256) void wperm_kernel(
    const _Float16* __restrict__ Wth, const _Float16* __restrict__ Wtl,
    _Float16* __restrict__ WpH, _Float16* __restrict__ WpL)
{
    const int blk = blockIdx.x;
    const int tid = threadIdx.x;
    const int k4 = tid * 4;
    for (int c = 0; c < 32; ++c) {
        half4 vh = (half4)(_Float16)0.f, vl = (half4)(_Float16)0.f;
        if (c < 20) {
            int unit = blk * 4 + c / 5, g = c % 5;
            size_t src = (size_t)(g * 512 + unit) * 1024 + k4;
            vh = *(const half4*)&Wth[src];
            vl = *(const half4*)&Wtl[src];
        }
        size_t dst = ((size_t)blk * 32 + c) * 1024 + k4;
        *(half4*)&WpH[dst] = vh;
        *(half4*)&WpL[dst] = vl;
    }
}

// ---------------- word GEMM: leaves -> h slots 0..31, leaf c, nodes ----------------
__global__ __launch_bounds__(256) void word_gemm64(
    const float* __restrict__ A, const float* __restrict__ W,
    const float* __restrict__ bias,
    _Float16* __restrict__ hi0, _Float16* __restrict__ lo0,
    float* __restrict__ cst, float* __restrict__ out)
{
    const int m0 = blockIdx.x * 64;
    const int n0 = blockIdx.y * 64;
    const int tid = threadIdx.x;
    const int tx = tid & 15, ty = tid >> 4;
    __shared__ float As[16][64];
    __shared__ float Bs[16][64];
    float acc[4][4];
#pragma unroll
    for (int i = 0; i < 4; ++i)
#pragma unroll
        for (int j = 0; j < 4; ++j) acc[i][j] = 0.f;

    for (int kt = 0; kt < ND; kt += 16) {
        {
            int row = tid >> 2, kq = tid & 3;
            float4 v = *(const float4*)(A + (size_t)(m0 + row) * ND + kt + kq * 4);
            As[kq * 4 + 0][row] = v.x;
            As[kq * 4 + 1][row] = v.y;
            As[kq * 4 + 2][row] = v.z;
            As[kq * 4 + 3][row] = v.w;
            int kr = tid >> 4, nq = tid & 15;
            float4 vb = *(const float4*)(W + (size_t)(kt + kr) * 1024 + n0 + nq * 4);
            *(float4*)&Bs[kr][nq * 4] = vb;
        }
        __syncthreads();
#pragma unroll
        for (int kk = 0; kk < 16; ++kk) {
            float a0 = As[kk][ty * 4 + 0], a1 = As[kk][ty * 4 + 1];
            float a2 = As[kk][ty * 4 + 2], a3 = As[kk][ty * 4 + 3];
            float4 bv = *(float4*)&Bs[kk][tx * 4];
            acc[0][0] = fmaf(a0, bv.x, acc[0][0]); acc[0][1] = fmaf(a0, bv.y, acc[0][1]);
            acc[0][2] = fmaf(a0, bv.z, acc[0][2]); acc[0][3] = fmaf(a0, bv.w, acc[0][3]);
            acc[1][0] = fmaf(a1, bv.x, acc[1][0]); acc[1][1] = fmaf(a1, bv.y, acc[1][1]);
            acc[1][2] = fmaf(a1, bv.z, acc[1][2]); acc[1][3] = fmaf(a1, bv.w, acc[1][3]);
            acc[2][0] = fmaf(a2, bv.x, acc[2][0]); acc[2][1] = fmaf(a2, bv.y, acc[2][1]);
            acc[2][2] = fmaf(a2, bv.z, acc[2][2]); acc[2][3] = fmaf(a2, bv.w, acc[2][3]);
            acc[3][0] = fmaf(a3, bv.x, acc[3][0]); acc[3][1] = fmaf(a3, bv.y, acc[3][1]);
            acc[3][2] = fmaf(a3, bv.z, acc[3][2]); acc[3][3] = fmaf(a3, bv.w, acc[3][3]);
        }
        __syncthreads();
    }
    float* nodes = out + 2 * BH;
#pragma unroll
    for (int i = 0; i < 4; ++i) {
        int r = m0 + ty * 4 + i;
        int b = r >> 5, l = r & 31;
#pragma unroll
        for (int jn = 0; jn < 4; ++jn) {
            int n = n0 + tx * 4 + jn;
            float v = acc[i][jn] + bias[n];
            if (n < NHID) {
                size_t si = ((size_t)l * NB + b) * NHID + n;
                _Float16 hh = (_Float16)v;
                hi0[si] = hh;
                lo0[si] = (_Float16)((v - (float)hh) * 2048.f);
                nodes[((size_t)b * 63 + l) * NHID + n] = v;
            } else {
                cst[((size_t)l * NB + b) * NHID + (n - NHID)] = v;
            }
        }
    }
}

// ---------------- persistent kernel: single-hop, redundant owner logic ----------------
// 128 blocks; block = 4 hidden units (20 gate cols in VGPR B panel). Per step:
// MFMA pair tiles -> activation (c in LDS) -> publish {h hi/lo, hF32, cF32,
// logit partial} (sc, write-once) -> bump striped counter -> poll counters ->
// EVERY block redundantly: read fresh partials (plain, write-once), fixed-order
// sum, all 32 per-batch argmaxes + bookkeeping in local LDS, build next entries
// locally. No owner round trip, no data-word polling.
__global__ __launch_bounds__(256, 1) void tree_loop(
    _Float16* __restrict__ hHi, _Float16* __restrict__ hLo,
    float* __restrict__ hF32, float* __restrict__ cF32,
    const _Float16* __restrict__ WpH, const _Float16* __restrict__ WpL,
    const float* __restrict__ bias, const float* __restrict__ q,
    const int* __restrict__ len, const float* __restrict__ cst,
    float* __restrict__ lpart, int* __restrict__ selLog, int* __restrict__ ireg)
{
    const int blk = blockIdx.x;
    const int tid = threadIdx.x;
    const int kw = tid >> 6, lane = tid & 63;
    const int l5 = lane >> 5, ln = lane & 31;

    int* gd = ireg;                        // 4 stripes at 0,32,64,96

    __shared__ float red[4][32][33];       // padded: no bank conflicts
    __shared__ unsigned s_entry[64];
    __shared__ float sH[32][4];
    __shared__ float sC[32][4];
    __shared__ float sLP[32];
    __shared__ float sBias[4][5];
    __shared__ float sQ[4];
    __shared__ float cB[NSLOTS][32][4];    // 64 KB block-private c-state slice
    __shared__ float plogP[32][32];        // [batch][position]
    __shared__ int pidxS[32][32];          // cand id per position
    __shared__ int hidxS[32][32];          // h slot per position
    __shared__ int prevkS[32];
    __shared__ int lenS[32];

    // B panel preload (once): 32 cols x 256 K per wave, hi+lo -> 128 VGPRs.
    const _Float16* bHiP = WpH + ((size_t)blk * 32 + ln) * 1024 + (kw << 8) + l5 * 8;
    const _Float16* bLoP = WpL + ((size_t)blk * 32 + ln) * 1024 + (kw << 8) + l5 * 8;
    half8 Bh[16], Bl[16];
#pragma unroll
    for (int ks = 0; ks < 16; ++ks) {
        Bh[ks] = *(const half8*)(bHiP + ks * 16);
        Bl[ks] = *(const half8*)(bLoP + ks * 16);
    }

    // bias/q slices
    if (tid < 20) { int ul = tid / 5, g = tid % 5; sBias[ul][g] = bias[g * 512 + blk * 4 + ul]; }
    if (tid >= 32 && tid < 36) sQ[tid - 32] = q[blk * 4 + (tid - 32)];
    if (tid >= 64 && tid < 96) lenS[tid - 64] = len[tid - 64];

    // c slice: leaves + zero slot
    for (int i = tid; i < 33 * 32 * 4; i += 256) {
        int slot = i >> 7, rem = i & 127;
        int b = rem >> 2, ul = rem & 3;
        cB[slot][b][ul] = (slot == SLOT_Z) ? 0.f
                          : cst[((size_t)slot * 32 + b) * 512 + blk * 4 + ul];
    }
    // bookkeeping init (replicated)
    for (int i = tid; i < 1024; i += 256) {
        int b = i >> 5, j = i & 31;
        pidxS[b][j] = 33 + min(j, 30);
        hidxS[b][j] = j;
    }
    __syncthreads();

    for (int step = 0; step < NSTEPS; ++step) {
        const int ntiles = (step == 0) ? 31 : 2;
        for (int t = 0; t < ntiles; ++t) {
            if (step == 0) {
                if (tid < 32) s_entry[tid] = pack_e(tid, 33 + t, t, t + 1);
                __syncthreads();
            }
            const unsigned* se = (step == 0) ? s_entry : s_entry + t * 32;
            // ---- MFMA: 32 pair rows x 32 cols (20 real) ----
            {
                const unsigned e = se[ln];
                const int eb = e & 31;
                const int lsl = (e >> 12) & 127, rsl = (e >> 19) & 127;
                const int hs = (kw < 2) ? lsl : rsl;
                const int koff = ((kw & 1) << 8) + l5 * 8;
                const _Float16* aHiP = hHi + ((size_t)hs * 32 + eb) * 512 + koff;
                const _Float16* aLoP = hLo + ((size_t)hs * 32 + eb) * 512 + koff;
                f32x16 acc1 = (f32x16)0.f, acc2 = (f32x16)0.f;
#pragma unroll
                for (int ks = 0; ks < 16; ++ks) {
                    half8 Ah = *(const half8*)(aHiP + ks * 16);
                    half8 Al = *(const half8*)(aLoP + ks * 16);
                    acc1 = __builtin_amdgcn_mfma_f32_32x32x16_f16(Ah, Bh[ks], acc1, 0, 0, 0);
                    acc2 = __builtin_amdgcn_mfma_f32_32x32x16_f16(Ah, Bl[ks], acc2, 0, 0, 0);
                    acc2 = __builtin_amdgcn_mfma_f32_32x32x16_f16(Al, Bh[ks], acc2, 0, 0, 0);
                }
                // C/D: col=lane&31, row=(a&3)+8*(a>>2)+4*(lane>>5)
#pragma unroll
                for (int a = 0; a < 16; ++a) {
                    int row = (a & 3) + 8 * (a >> 2) + 4 * l5;
                    red[kw][row][ln] = acc1[a] + acc2[a] * INV2048;
                }
            }
            __syncthreads();
            // ---- activation: thread (row r, unit ul) ----
            if (tid < 128) {
                const int r = tid >> 2, ul = tid & 3;
                const unsigned e = se[r];
                const int eb = e & 31, cand = (e >> 5) & 127;
                const int lsl = (e >> 12) & 127, rsl = (e >> 19) & 127;
                const int c0 = ul * 5;
                float g0 = (red[0][r][c0+0] + red[1][r][c0+0]) + (red[2][r][c0+0] + red[3][r][c0+0]);
                float g1 = (red[0][r][c0+1] + red[1][r][c0+1]) + (red[2][r][c0+1] + red[3][r][c0+1]);
                float g2 = (red[0][r][c0+2] + red[1][r][c0+2]) + (red[2][r][c0+2] + red[3][r][c0+2]);
                float g3 = (red[0][r][c0+3] + red[1][r][c0+3]) + (red[2][r][c0+3] + red[3][r][c0+3]);
                float g4 = (red[0][r][c0+4] + red[1][r][c0+4]) + (red[2][r][c0+4] + red[3][r][c0+4]);
                float ig = g0 + sBias[ul][0];
                float fl = g1 + sBias[ul][1];
                float fr = g2 + sBias[ul][2];
                float uu = g3 + sBias[ul][3];
                float oo = g4 + sBias[ul][4];
                float cl = cB[lsl][eb][ul];
                float cr = cB[rsl][eb][ul];
                float c = cl * sigf(fl + 1.f) + cr * sigf(fr + 1.f) + tanhf(uu) * sigf(ig);
                float h = sigf(oo) * tanhf(c);
                cB[cand][eb][ul] = c;
                sC[r][ul] = c;
                sH[r][ul] = h;
                float p = h * sQ[ul];
                p += __shfl_down(p, 1);
                p += __shfl_down(p, 2);
                if (ul == 0) sLP[r] = p;
            }
            __syncthreads();
            // ---- publish (sc, write-once): h hi/lo, hF32, cF32, logit partial ----
            if (tid < 32) {
                const unsigned e = se[tid];
                const int eb = e & 31, cand = (e >> 5) & 127;
                float x0 = sH[tid][0], x1 = sH[tid][1], x2 = sH[tid][2], x3 = sH[tid][3];
                half4 hv, lv;
                {
                    _Float16 h0 = (_Float16)x0, h1 = (_Float16)x1,
                             h2 = (_Float16)x2, h3 = (_Float16)x3;
                    hv[0] = h0; hv[1] = h1; hv[2] = h2; hv[3] = h3;
                    lv[0] = (_Float16)((x0 - (float)h0) * 2048.f);
                    lv[1] = (_Float16)((x1 - (float)h1) * 2048.f);
                    lv[2] = (_Float16)((x2 - (float)h2) * 2048.f);
                    lv[3] = (_Float16)((x3 - (float)h3) * 2048.f);
                }
                const size_t so = ((size_t)cand * 32 + eb) * 512 + blk * 4;
                st_sc64(&hHi[so], __builtin_bit_cast(u64, hv));
                st_sc64(&hLo[so], __builtin_bit_cast(u64, lv));
                st_sc64(&hF32[so],     (u64)__float_as_uint(x0) | ((u64)__float_as_uint(x1) << 32));
                st_sc64(&hF32[so + 2], (u64)__float_as_uint(x2) | ((u64)__float_as_uint(x3) << 32));
                st_sc64(&cF32[so],     (u64)__float_as_uint(sC[tid][0]) | ((u64)__float_as_uint(sC[tid][1]) << 32));
                st_sc64(&cF32[so + 2], (u64)__float_as_uint(sC[tid][2]) | ((u64)__float_as_uint(sC[tid][3]) << 32));
                st_sc32f(&lpart[((size_t)cand * 32 + eb) * 128 + blk], sLP[tid]);
            }
            __syncthreads();
        }
        // drain wave-0 publishes, bump striped counter
        if (tid == 0) {
            asm volatile("s_waitcnt vmcnt(0)" ::: "memory");
            __hip_atomic_fetch_add(&gd[(blk & 3) * 32], 1, __ATOMIC_RELAXED,
                                   __HIP_MEMORY_SCOPE_AGENT);
        }
        // single hop: poll striped counters only (no data-word polling)
        if (tid < 4) {
            const int tgt = 32 * (step + 1);
            while (ld_sc(&gd[tid * 32]) < tgt) __builtin_amdgcn_s_sleep(1);
        }
        __syncthreads();

        // ---- redundant owner logic (every block, identical data & order) ----
        // fresh logits: fixed-order sum of 128 partials
        if (step == 0) {
            for (int idx = tid; idx < 992; idx += 256) {
                int b = idx & 31, j = idx >> 5;
                const float4* pp = (const float4*)&lpart[((size_t)(33 + j) * 32 + b) * 128];
                float s = 0.f;
                for (int i = 0; i < 32; ++i) {
                    float4 v = pp[i];
                    s += (v.x + v.y) + (v.z + v.w);
                }
                plogP[b][j] = s;
            }
        } else {
            if (tid < 64) {
                int b = tid >> 1, f = tid & 1;
                int pk = prevkS[b];
                if (pk >= 0 && (f == 1 || pk >= 1)) {
                    int cand = (f == 1) ? 65 + 2 * (step - 1) : 64 + 2 * (step - 1);
                    int pos  = (f == 1) ? pk : pk - 1;
                    const float4* pp = (const float4*)&lpart[((size_t)cand * 32 + b) * 128];
                    float s = 0.f;
                    for (int i = 0; i < 32; ++i) {
                        float4 v = pp[i];
                        s += (v.x + v.y) + (v.z + v.w);
                    }
                    plogP[b][pos] = s;
                }
            }
        }
        __syncthreads();

        // per-batch argmax + bookkeeping + next entries (thread b handles batch b)
        if (tid < 32) {
            const int b = tid;
            const int actb = lenS[b] - 1 - step;
            const int merge = actb >= 1;
            const int last = (step == NSTEPS - 1);
            int selB;
            const unsigned dummy = pack_e(b, SLOT_DUMMY, SLOT_Z, SLOT_Z);
            if (merge) {
                int n = min(actb, 31);
                float best = -1e30f;
                int k = 0;
                for (int j = 0; j < n; ++j) {
                    float v = plogP[b][j];
                    if (v > best) { best = v; k = j; }   // strict > keeps first index
                }
                const int winner = pidxS[b][k];
                selB = winner;
                const int candA = 64 + 2 * step, candB = 65 + 2 * step;
                if (!last) {
                    s_entry[2 * b] = (k >= 1)
                        ? pack_e(b, candA, hidxS[b][k - 1], winner) : dummy;
                    s_entry[2 * b + 1] = pack_e(b, candB, winner,
                                                (k + 2 <= 31) ? hidxS[b][k + 2] : SLOT_Z);
                }
                if (k >= 1) pidxS[b][k - 1] = candA;
                pidxS[b][k] = candB;
                hidxS[b][k] = winner;
                for (int j = k + 1; j <= 30; ++j) hidxS[b][j] = hidxS[b][j + 1];
                hidxS[b][31] = SLOT_Z;
                for (int j = k + 1; j <= 29; ++j) {
                    pidxS[b][j] = pidxS[b][j + 1];
                    plogP[b][j] = plogP[b][j + 1];
                }
                prevkS[b] = k;
            } else {
                if (!last) { s_entry[2 * b] = dummy; s_entry[2 * b + 1] = dummy; }
                selB = last ? hidxS[b][0] : pidxS[b][0];
                prevkS[b] = -1;
            }
            if (blk == 0) selLog[step * 32 + b] = selB;   // plain store; boundary flush
        }
        __syncthreads();
    }
}

// ---------------- gather: nodes rows, hf, cf (off critical path) ----------------
__global__ __launch_bounds__(256) void gather_kernel(
    const float* __restrict__ hF32, const float* __restrict__ cF32,
    const float* __restrict__ cst, const int* __restrict__ selLog,
    float* __restrict__ out)
{
    const int b = blockIdx.x;
    const int tid = threadIdx.x;
    float* nodes = out + 2 * BH;
    for (int s = 0; s < NSTEPS; ++s) {
        const int id = selLog[s * 32 + b];
        float* dst = nodes + ((size_t)b * 63 + 32 + s) * 512;
        const float* src = (id < 32) ? nodes + ((size_t)b * 63 + id) * 512
                                     : hF32 + ((size_t)id * 32 + b) * 512;
        for (int u = tid; u < 512; u += 256) dst[u] = src[u];
    }
    const int rid = selLog[30 * 32 + b];
    const float* hsrc = (rid < 32) ? nodes + ((size_t)b * 63 + rid) * 512
                                   : hF32 + ((size_t)rid * 32 + b) * 512;
    const float* csrc = (rid < 32) ? cst + ((size_t)rid * 32 + b) * 512
                                   : cF32 + ((size_t)rid * 32 + b) * 512;
    for (int u = tid; u < 512; u += 256) {
        out[b * 512 + u] = hsrc[u];
        out[BH + b * 512 + u] = csrc[u];
    }
}

extern "C" void kernel_launch(void* const* d_in, const int* in_sizes, int n_in,
                              void* d_out, int out_size, void* d_ws, size_t ws_size,
                              hipStream_t stream) {
    const float* inp    = (const float*)d_in[0];
    const int*   length = (const int*)d_in[1];
    const float* W_word = (const float*)d_in[2];
    const float* b_word = (const float*)d_in[3];
    const float* W_comp = (const float*)d_in[4];
    const float* b_comp = (const float*)d_in[5];
    const float* q      = (const float*)d_in[6];
    float* out = (float*)d_out;
    float* ws  = (float*)d_ws;

    _Float16*  Wth  = (_Float16*)(ws + OFF_WTH);
    _Float16*  Wtl  = (_Float16*)(ws + OFF_WTL);
    _Float16*  WpH  = (_Float16*)(ws + OFF_WPH);
    _Float16*  WpL  = (_Float16*)(ws + OFF_WPL);
    _Float16*  hHi  = (_Float16*)(ws + OFF_HHI);
    _Float16*  hLo  = (_Float16*)(ws + OFF_HLO);
    float*     hF32 = ws + OFF_HF32;
    float*     cF32 = ws + OFF_CF32;
    float*     cst  = ws + OFF_CST;
    float*     lpart= ws + OFF_LPART;
    int*       selLog = (int*)(ws + OFF_SEL);
    int*       ireg   = (int*)(ws + OFF_IREG);

    init_kernel<<<1, 256, 0, stream>>>(ireg, hHi, hLo);
    wsplit_kernel<<<dim3(NC5 / 32, 1024 / 32), 256, 0, stream>>>(W_comp, Wth, Wtl);
    wperm_kernel<<<128, 256, 0, stream>>>(Wth, Wtl, WpH, WpL);
    word_gemm64<<<dim3(16, 16), 256, 0, stream>>>(inp, W_word, b_word,
                                                  hHi, hLo, cst, out);
    tree_loop<<<NBLK, 256, 0, stream>>>(hHi, hLo, hF32, cF32, WpH, WpL, b_comp, q,
                                        length, cst, lpart, selLog, ireg);
    gather_kernel<<<NB, 256, 0, stream>>>(hF32, cF32, cst, selLog, out);
}

// Round 9
// 615.746 us; speedup vs baseline: 1.3035x; 1.3035x over previous
//
#include <hip/hip_runtime.h>
#include <math.h>

// Problem constants
constexpr int NB = 32, ND = 512, NHID = 512, NSTEPS = 31;
constexpr int NC5 = 2560;          // 5H
constexpr int BH = NB * NHID;      // 16384
constexpr int SLOT_Z = 32;         // zero h/c slot (per-team slot space)
constexpr int SLOT_DUMMY = 126;    // dummy candidate (written, never read)
constexpr int NSLOTS = 128;        // 0..31 leaves, 32 zero, 33..63 step0 cands,
                                   // 64+2s/65+2s cands born at step s+1, 126 dummy
constexpr float INV2048 = 1.f / 2048.f;

typedef _Float16 half8  __attribute__((ext_vector_type(8)));
typedef _Float16 half4  __attribute__((ext_vector_type(4)));
typedef _Float16 half2t __attribute__((ext_vector_type(2)));
typedef float    f32x16 __attribute__((ext_vector_type(16)));
typedef unsigned long long u64;

// ---------------- workspace layout (float offsets) ----------------
constexpr size_t OFF_WTH  = 0;                                     // [2560][1024] halves
constexpr size_t OFF_WTL  = OFF_WTH + (size_t)NC5 * 1024 / 2;
constexpr size_t OFF_WPH  = OFF_WTL + (size_t)NC5 * 1024 / 2;      // [32 rank][96][1024] halves
constexpr size_t OFF_WPL  = OFF_WPH + (size_t)32 * 96 * 1024 / 2;
constexpr size_t OFF_HTH  = OFF_WPL + (size_t)32 * 96 * 1024 / 2;  // [8][128][4][512] halves
constexpr size_t OFF_HTL  = OFF_HTH + (size_t)8 * 128 * 4 * 512 / 2;
constexpr size_t OFF_HF32 = OFF_HTL + (size_t)8 * 128 * 4 * 512 / 2; // [8][128][4][512] f32
constexpr size_t OFF_CF32 = OFF_HF32 + (size_t)8 * 128 * 4 * 512;
constexpr size_t OFF_CST  = OFF_CF32 + (size_t)8 * 128 * 4 * 512;  // leaf c [32][32][512]
constexpr size_t OFF_LPART= OFF_CST + (size_t)32 * 32 * 512;       // [8][128][4][32] f32
constexpr size_t OFF_SEL  = OFF_LPART + (size_t)8 * 128 * 4 * 32;  // int [31][32]
constexpr size_t OFF_IREG = OFF_SEL + 1024;                        // 2048 ints

// ireg: tix[xcd] at xcd*32 (0..255); gd[xcd][stripe] at 256 + xcd*128 + stripe*32
__device__ __forceinline__ float sigf(float x) { return 1.f / (1.f + expf(-x)); }

__device__ __forceinline__ int ld_ag(const int* p) {
    return __hip_atomic_load(p, __ATOMIC_RELAXED, __HIP_MEMORY_SCOPE_AGENT);
}
__device__ __forceinline__ int add_ag(int* p, int v) {
    return __hip_atomic_fetch_add(p, v, __ATOMIC_RELAXED, __HIP_MEMORY_SCOPE_AGENT);
}
// entry pack: b4[0:2) cand[2:9) l[9:16) r[16:23)
__device__ __forceinline__ unsigned pack_e(int b4, int cand, int l, int r) {
    return (unsigned)b4 | ((unsigned)cand << 2) | ((unsigned)l << 9) | ((unsigned)r << 16);
}

// ---------------- init: int region, zero h slot for all teams ----------------
__global__ __launch_bounds__(256) void init_kernel(
    int* __restrict__ ireg, _Float16* __restrict__ hTH, _Float16* __restrict__ hTL)
{
    const int blk = blockIdx.x, tid = threadIdx.x;
    if (blk == 0) {
        for (int i = tid; i < 2048; i += 256) ireg[i] = 0;
    } else {
        // zero slot 32 of every team/batch: [x][32][b4][512]
        for (int i = tid; i < 8 * 4 * 512; i += 256) {
            int x = i >> 11, rem = i & 2047;
            size_t o = (((size_t)x * 128 + SLOT_Z) * 4) * 512 + rem;
            hTH[o] = (_Float16)0.f;
            hTL[o] = (_Float16)0.f;
        }
    }
}

// ---------------- W_comp -> transposed split fp16 planes ----------------
__global__ __launch_bounds__(256) void wsplit_kernel(
    const float* __restrict__ W, _Float16* __restrict__ Wth, _Float16* __restrict__ Wtl)
{
    __shared__ float t[32][33];
    const int n0 = blockIdx.x * 32, k0 = blockIdx.y * 32;
    const int tid = threadIdx.x;
    const int c = tid & 31, r8 = tid >> 5;
#pragma unroll
    for (int p = 0; p < 4; ++p) {
        int r = p * 8 + r8;
        t[r][c] = W[(size_t)(k0 + r) * NC5 + n0 + c];
    }
    __syncthreads();
    const int nl = tid >> 3, k4 = (tid & 7) * 4;
    half4 vh, vl;
#pragma unroll
    for (int i = 0; i < 4; ++i) {
        float v = t[k4 + i][nl];
        _Float16 hh = (_Float16)v;
        vh[i] = hh;
        vl[i] = (_Float16)((v - (float)hh) * 2048.f);
    }
    size_t o = (size_t)(n0 + nl) * 1024 + k0 + k4;
    *(half4*)&Wth[o] = vh;
    *(half4*)&Wtl[o] = vl;
}

// ---------------- permute W^T into per-rank unit-gate panels ----------------
// rank owns units rank*16..+15; col c<80: unit_local=c/5, gate=c%5,
// source row n = gate*512 + rank*16 + unit_local. Cols 80..95 zero.
__global__ __launch_bounds__(256) void wperm_kernel(
    const _Float16* __restrict__ Wth, const _Float16* __restrict__ Wtl,
    _Float16* __restrict__ WpH, _Float16* __restrict__ WpL)
{
    const int rank = blockIdx.x;
    const int tid = threadIdx.x;
    const int k4 = tid * 4;
    for (int c = 0; c < 96; ++c) {
        half4 vh = (half4)(_Float16)0.f, vl = (half4)(_Float16)0.f;
        if (c < 80) {
            int ul = c / 5, g = c % 5;
            size_t src = (size_t)(g * 512 + rank * 16 + ul) * 1024 + k4;
            vh = *(const half4*)&Wth[src];
            vl = *(const half4*)&Wtl[src];
        }
        size_t dst = ((size_t)rank * 96 + c) * 1024 + k4;
        *(half4*)&WpH[dst] = vh;
        *(half4*)&WpL[dst] = vl;
    }
}

// ---------------- word GEMM: leaves -> team h slots 0..31, leaf c, nodes ----------------
__global__ __launch_bounds__(256) void word_gemm64(
    const float* __restrict__ A, const float* __restrict__ W,
    const float* __restrict__ bias,
    _Float16* __restrict__ hTH, _Float16* __restrict__ hTL,
    float* __restrict__ cst, float* __restrict__ out)
{
    const int m0 = blockIdx.x * 64;
    const int n0 = blockIdx.y * 64;
    const int tid = threadIdx.x;
    const int tx = tid & 15, ty = tid >> 4;
    __shared__ float As[16][64];
    __shared__ float Bs[16][64];
    float acc[4][4];
#pragma unroll
    for (int i = 0; i < 4; ++i)
#pragma unroll
        for (int j = 0; j < 4; ++j) acc[i][j] = 0.f;

    for (int kt = 0; kt < ND; kt += 16) {
        {
            int row = tid >> 2, kq = tid & 3;
            float4 v = *(const float4*)(A + (size_t)(m0 + row) * ND + kt + kq * 4);
            As[kq * 4 + 0][row] = v.x;
            As[kq * 4 + 1][row] = v.y;
            As[kq * 4 + 2][row] = v.z;
            As[kq * 4 + 3][row] = v.w;
            int kr = tid >> 4, nq = tid & 15;
            float4 vb = *(const float4*)(W + (size_t)(kt + kr) * 1024 + n0 + nq * 4);
            *(float4*)&Bs[kr][nq * 4] = vb;
        }
        __syncthreads();
#pragma unroll
        for (int kk = 0; kk < 16; ++kk) {
            float a0 = As[kk][ty * 4 + 0], a1 = As[kk][ty * 4 + 1];
            float a2 = As[kk][ty * 4 + 2], a3 = As[kk][ty * 4 + 3];
            float4 bv = *(float4*)&Bs[kk][tx * 4];
            acc[0][0] = fmaf(a0, bv.x, acc[0][0]); acc[0][1] = fmaf(a0, bv.y, acc[0][1]);
            acc[0][2] = fmaf(a0, bv.z, acc[0][2]); acc[0][3] = fmaf(a0, bv.w, acc[0][3]);
            acc[1][0] = fmaf(a1, bv.x, acc[1][0]); acc[1][1] = fmaf(a1, bv.y, acc[1][1]);
            acc[1][2] = fmaf(a1, bv.z, acc[1][2]); acc[1][3] = fmaf(a1, bv.w, acc[1][3]);
            acc[2][0] = fmaf(a2, bv.x, acc[2][0]); acc[2][1] = fmaf(a2, bv.y, acc[2][1]);
            acc[2][2] = fmaf(a2, bv.z, acc[2][2]); acc[2][3] = fmaf(a2, bv.w, acc[2][3]);
            acc[3][0] = fmaf(a3, bv.x, acc[3][0]); acc[3][1] = fmaf(a3, bv.y, acc[3][1]);
            acc[3][2] = fmaf(a3, bv.z, acc[3][2]); acc[3][3] = fmaf(a3, bv.w, acc[3][3]);
        }
        __syncthreads();
    }
    float* nodes = out + 2 * BH;
#pragma unroll
    for (int i = 0; i < 4; ++i) {
        int r = m0 + ty * 4 + i;
        int b = r >> 5, l = r & 31;
#pragma unroll
        for (int jn = 0; jn < 4; ++jn) {
            int n = n0 + tx * 4 + jn;
            float v = acc[i][jn] + bias[n];
            if (n < NHID) {
                size_t si = (((size_t)(b >> 2) * 128 + l) * 4 + (b & 3)) * 512 + n;
                _Float16 hh = (_Float16)v;
                hTH[si] = hh;
                hTL[si] = (_Float16)((v - (float)hh) * 2048.f);
                nodes[((size_t)b * 63 + l) * NHID + n] = v;
            } else {
                cst[((size_t)l * NB + b) * NHID + (n - NHID)] = v;
            }
        }
    }
}

// ---------------- persistent XCD-team kernel ----------------
// 256 blocks, ~400 VGPR + >80KB LDS force 1 block/CU -> exactly 32 blocks/XCD.
// Team = the 32 blocks sharing an XCC_ID (hardware register); team handles
// batches xcd*4..+3. Block rank (ticket) owns units rank*16..+15 (80 gate
// cols; groups 0-1 in VGPRs, group 2 streamed from L2). All step payloads are
// plain stores/loads through the team's shared L2 (write-once slots); only the
// per-team arrival counters are agent-scope. Teams are fully decoupled.
__global__ __launch_bounds__(256, 1) void tree_loop(
    _Float16* __restrict__ hTH, _Float16* __restrict__ hTL,
    float* __restrict__ hF32, float* __restrict__ cF32,
    const _Float16* __restrict__ WpH, const _Float16* __restrict__ WpL,
    const float* __restrict__ bias, const float* __restrict__ q,
    const int* __restrict__ len, const float* __restrict__ cst,
    float* __restrict__ lpart, int* __restrict__ selLog, int* __restrict__ ireg)
{
    const int tid = threadIdx.x;
    const int kw = tid >> 6, lane = tid & 63;
    const int l5 = lane >> 5, ln = lane & 31;

    __shared__ float red[4][32][91];       // 46.6 KB (stride 91: odd mod 32)
    __shared__ float cB[NSLOTS][4][16];    // 32 KB block-private c slice
    __shared__ float sBias[16][5];
    __shared__ float sQ[16];
    __shared__ unsigned s_entry[32];
    __shared__ float sLPp[32][8];
    __shared__ float plogP[4][32];
    __shared__ int pidxS[4][32], hidxS[4][32];
    __shared__ int prevkS[4], len4[4];
    __shared__ int s_xcd, s_rank;

    // ---- team formation: hardware XCD id + one-time device-scope ticket ----
    if (tid == 0) {
        int xcd = __builtin_amdgcn_s_getreg((31 << 11) | (0 << 6) | 20) & 7; // HW_REG_XCC_ID
        s_xcd = xcd;
        s_rank = add_ag(&ireg[xcd * 32], 1) & 31;
    }
    __syncthreads();
    const int xcd = s_xcd, rank = s_rank;
    int* gdp = ireg + 256 + xcd * 128;

    // preload bias/q/len/bookkeeping
    if (tid < 80) { int ul = tid / 5, g = tid % 5; sBias[ul][g] = bias[g * 512 + rank * 16 + ul]; }
    if (tid >= 96 && tid < 112) sQ[tid - 96] = q[rank * 16 + (tid - 96)];
    if (tid >= 112 && tid < 116) { len4[tid - 112] = len[xcd * 4 + (tid - 112)]; prevkS[tid - 112] = 0; }
    for (int i = tid; i < 33 * 4 * 16; i += 256) {
        int slot = i >> 6, b4 = (i >> 4) & 3, u = i & 15;
        cB[slot][b4][u] = (slot == SLOT_Z) ? 0.f
            : cst[((size_t)slot * NB + xcd * 4 + b4) * 512 + rank * 16 + u];
    }
    for (int i = tid; i < 128; i += 256) {
        int b4 = i >> 5, j = i & 31;
        pidxS[b4][j] = 33 + min(j, 30);
        hidxS[b4][j] = j;
    }

    // ---- B panel: groups 0,1 resident in VGPRs; group 2 streamed ----
    const size_t wb = ((size_t)rank * 96) * 1024 + ((size_t)kw << 8) + l5 * 8;
    half8 Bh[2][16], Bl[2][16];
#pragma unroll
    for (int g = 0; g < 2; ++g)
#pragma unroll
        for (int ks = 0; ks < 16; ++ks) {
            Bh[g][ks] = *(const half8*)(WpH + wb + (size_t)(g * 32 + ln) * 1024 + ks * 16);
            Bl[g][ks] = *(const half8*)(WpL + wb + (size_t)(g * 32 + ln) * 1024 + ks * 16);
        }
    const _Float16* b2HiP = WpH + wb + (size_t)(64 + ln) * 1024;
    const _Float16* b2LoP = WpL + wb + (size_t)(64 + ln) * 1024;

    const size_t hbase = (size_t)xcd * 128 * 4 * 512;
    const size_t lpbase = (size_t)xcd * 128 * 4 * 32;
    __syncthreads();

    for (int step = 0; step < NSTEPS; ++step) {
        const int last = (step == NSTEPS - 1);
        const int ntiles = (step == 0) ? 4 : 1;
        for (int t = 0; t < ntiles; ++t) {
            if (step == 0) {
                if (tid < 32) {
                    int idx = t * 32 + tid, j = idx >> 2, b4 = idx & 3;
                    s_entry[tid] = (j <= 30) ? pack_e(b4, 33 + j, j, j + 1)
                                             : pack_e(0, SLOT_DUMMY, SLOT_Z, SLOT_Z);
                }
                __syncthreads();
            }
            // ---- MFMA: 32 rows x 80 cols (3 groups), split-fp16 3-product ----
            {
                const unsigned e = s_entry[ln];
                const int eb4 = e & 3;
                const int lsl = (e >> 9) & 127, rsl = (e >> 16) & 127;
                const int hs = (kw < 2) ? lsl : rsl;
                const int koff = ((kw & 1) << 8) + l5 * 8;
                const _Float16* aHiP = hTH + hbase + ((size_t)hs * 4 + eb4) * 512 + koff;
                const _Float16* aLoP = hTL + hbase + ((size_t)hs * 4 + eb4) * 512 + koff;
#pragma unroll
                for (int g = 0; g < 2; ++g) {
                    f32x16 acc1 = (f32x16)0.f, acc2 = (f32x16)0.f;
#pragma unroll
                    for (int ks = 0; ks < 16; ++ks) {
                        half8 Ah = *(const half8*)(aHiP + ks * 16);
                        half8 Al = *(const half8*)(aLoP + ks * 16);
                        acc1 = __builtin_amdgcn_mfma_f32_32x32x16_f16(Ah, Bh[g][ks], acc1, 0, 0, 0);
                        acc2 = __builtin_amdgcn_mfma_f32_32x32x16_f16(Ah, Bl[g][ks], acc2, 0, 0, 0);
                        acc2 = __builtin_amdgcn_mfma_f32_32x32x16_f16(Al, Bh[g][ks], acc2, 0, 0, 0);
                    }
#pragma unroll
                    for (int a = 0; a < 16; ++a) {
                        int row = (a & 3) + 8 * (a >> 2) + 4 * l5;
                        red[kw][row][g * 32 + ln] = acc1[a] + acc2[a] * INV2048;
                    }
                }
                {   // group 2: cols 64..79 real (80..95 zero), B streamed from L2
                    f32x16 acc1 = (f32x16)0.f, acc2 = (f32x16)0.f;
#pragma unroll
                    for (int ks = 0; ks < 16; ++ks) {
                        half8 Ah = *(const half8*)(aHiP + ks * 16);
                        half8 Al = *(const half8*)(aLoP + ks * 16);
                        half8 B2h = *(const half8*)(b2HiP + ks * 16);
                        half8 B2l = *(const half8*)(b2LoP + ks * 16);
                        acc1 = __builtin_amdgcn_mfma_f32_32x32x16_f16(Ah, B2h, acc1, 0, 0, 0);
                        acc2 = __builtin_amdgcn_mfma_f32_32x32x16_f16(Ah, B2l, acc2, 0, 0, 0);
                        acc2 = __builtin_amdgcn_mfma_f32_32x32x16_f16(Al, B2h, acc2, 0, 0, 0);
                    }
                    if (ln < 16) {
#pragma unroll
                        for (int a = 0; a < 16; ++a) {
                            int row = (a & 3) + 8 * (a >> 2) + 4 * l5;
                            red[kw][row][64 + ln] = acc1[a] + acc2[a] * INV2048;
                        }
                    }
                }
            }
            __syncthreads();
            // ---- activation + publish: thread (row r, unit pair up) ----
            {
                const int r = tid & 31, up = tid >> 5;       // up 0..7 -> units 2up,2up+1
                const unsigned e = s_entry[r];
                const int eb4 = e & 3, cand = (e >> 2) & 127;
                const int lsl = (e >> 9) & 127, rsl = (e >> 16) & 127;
                float hva[2], cva[2];
                float p = 0.f;
#pragma unroll
                for (int i = 0; i < 2; ++i) {
                    const int u = 2 * up + i;
                    const int c0 = u * 5;
                    float g0 = (red[0][r][c0+0] + red[1][r][c0+0]) + (red[2][r][c0+0] + red[3][r][c0+0]);
                    float g1 = (red[0][r][c0+1] + red[1][r][c0+1]) + (red[2][r][c0+1] + red[3][r][c0+1]);
                    float g2 = (red[0][r][c0+2] + red[1][r][c0+2]) + (red[2][r][c0+2] + red[3][r][c0+2]);
                    float g3 = (red[0][r][c0+3] + red[1][r][c0+3]) + (red[2][r][c0+3] + red[3][r][c0+3]);
                    float g4 = (red[0][r][c0+4] + red[1][r][c0+4]) + (red[2][r][c0+4] + red[3][r][c0+4]);
                    float ig = g0 + sBias[u][0];
                    float fl = g1 + sBias[u][1];
                    float fr = g2 + sBias[u][2];
                    float uu = g3 + sBias[u][3];
                    float oo = g4 + sBias[u][4];
                    float cl = cB[lsl][eb4][u], cr = cB[rsl][eb4][u];
                    float c = cl * sigf(fl + 1.f) + cr * sigf(fr + 1.f) + tanhf(uu) * sigf(ig);
                    float h = sigf(oo) * tanhf(c);
                    cB[cand][eb4][u] = c;
                    hva[i] = h; cva[i] = c;
                    p = fmaf(h, sQ[u], p);
                }
                sLPp[r][up] = p;
                // plain stores into team L2 (write-once slots)
                const size_t base = hbase + ((size_t)cand * 4 + eb4) * 512 + rank * 16 + 2 * up;
                half2t hv, lv;
                hv[0] = (_Float16)hva[0]; hv[1] = (_Float16)hva[1];
                lv[0] = (_Float16)((hva[0] - (float)hv[0]) * 2048.f);
                lv[1] = (_Float16)((hva[1] - (float)hv[1]) * 2048.f);
                *(half2t*)&hTH[base] = hv;
                *(half2t*)&hTL[base] = lv;
                *(float2*)&hF32[base] = make_float2(hva[0], hva[1]);
                *(float2*)&cF32[base] = make_float2(cva[0], cva[1]);
            }
            __syncthreads();
            if (tid < 32) {        // per-row logit partial for this rank
                float s = ((sLPp[tid][0] + sLPp[tid][1]) + (sLPp[tid][2] + sLPp[tid][3]))
                        + ((sLPp[tid][4] + sLPp[tid][5]) + (sLPp[tid][6] + sLPp[tid][7]));
                const unsigned e = s_entry[tid];
                lpart[lpbase + (((size_t)((e >> 2) & 127)) * 4 + (e & 3)) * 32 + rank] = s;
            }
            __syncthreads();
        }
        // ---- team handoff: drain (barrier) -> agent counter bump -> poll ----
        if (tid == 0) add_ag(&gdp[(rank & 3) * 32], 1);
        if (tid < 4) {
            const int tgt = 8 * (step + 1);
            while (ld_ag(&gdp[tid * 32]) < tgt) __builtin_amdgcn_s_sleep(2);
        }
        __syncthreads();

        // ---- redundant owner logic (every block, fixed order -> identical) ----
        if (step == 0) {
            if (tid < 124) {
                int j = tid >> 2, b4 = tid & 3;
                const float4* pp = (const float4*)&lpart[lpbase + ((size_t)(33 + j) * 4 + b4) * 32];
                float s = 0.f;
#pragma unroll
                for (int i = 0; i < 8; ++i) {
                    float4 v = pp[i];
                    s += (v.x + v.y) + (v.z + v.w);
                }
                plogP[b4][j] = s;
            }
        } else {
            if (tid < 8) {
                int b4 = tid >> 1, f = tid & 1;
                int pk = prevkS[b4];
                if (pk >= 0 && (f == 1 || pk >= 1)) {
                    int cand = (f ? 65 : 64) + 2 * (step - 1);
                    int pos = f ? pk : pk - 1;
                    const float4* pp = (const float4*)&lpart[lpbase + ((size_t)cand * 4 + b4) * 32];
                    float s = 0.f;
#pragma unroll
                    for (int i = 0; i < 8; ++i) {
                        float4 v = pp[i];
                        s += (v.x + v.y) + (v.z + v.w);
                    }
                    plogP[b4][pos] = s;
                }
            }
        }
        __syncthreads();

        if (tid < 4) {
            const int b4 = tid;
            const int actb = len4[b4] - 1 - step;
            const int merge = actb >= 1;
            int selB;
            const unsigned dummy = pack_e(0, SLOT_DUMMY, SLOT_Z, SLOT_Z);
            if (merge) {
                int n = min(actb, 31);
                float best = -1e30f;
                int k = 0;
                for (int j = 0; j < n; ++j) {
                    float v = plogP[b4][j];
                    if (v > best) { best = v; k = j; }   // strict > keeps first index
                }
                const int winner = pidxS[b4][k];
                selB = winner;
                const int candA = 64 + 2 * step, candB = 65 + 2 * step;
                if (!last) {
                    s_entry[2 * b4] = (k >= 1)
                        ? pack_e(b4, candA, hidxS[b4][k - 1], winner) : dummy;
                    s_entry[2 * b4 + 1] = pack_e(b4, candB, winner,
                                                 (k + 2 <= 31) ? hidxS[b4][k + 2] : SLOT_Z);
                }
                if (k >= 1) pidxS[b4][k - 1] = candA;
                pidxS[b4][k] = candB;
                hidxS[b4][k] = winner;
                for (int j = k + 1; j <= 30; ++j) hidxS[b4][j] = hidxS[b4][j + 1];
                hidxS[b4][31] = SLOT_Z;
                for (int j = k + 1; j <= 29; ++j) {
                    pidxS[b4][j] = pidxS[b4][j + 1];
                    plogP[b4][j] = plogP[b4][j + 1];
                }
                prevkS[b4] = k;
            } else {
                if (!last) { s_entry[2 * b4] = dummy; s_entry[2 * b4 + 1] = dummy; }
                selB = last ? hidxS[b4][0] : pidxS[b4][0];
                prevkS[b4] = -1;
            }
            if (rank == 0) selLog[step * 32 + xcd * 4 + b4] = selB;
        }
        if (tid >= 8 && tid < 32 && !last)
            s_entry[tid] = pack_e(0, SLOT_DUMMY, SLOT_Z, SLOT_Z);
        __syncthreads();
    }
}

// ---------------- gather: node rows, hf, cf (off critical path) ----------------
__global__ __launch_bounds__(256) void gather_kernel(
    const float* __restrict__ hF32, const float* __restrict__ cF32,
    const float* __restrict__ cst, const int* __restrict__ selLog,
    float* __restrict__ out)
{
    const int b = blockIdx.x;
    const int tid = threadIdx.x;
    const int x = b >> 2, b4 = b & 3;
    float* nodes = out + 2 * BH;
    for (int s = 0; s < NSTEPS; ++s) {
        const int id = selLog[s * 32 + b];
        float* dst = nodes + ((size_t)b * 63 + 32 + s) * 512;
        const float* src = (id < 32) ? nodes + ((size_t)b * 63 + id) * 512
                                     : hF32 + (((size_t)x * 128 + id) * 4 + b4) * 512;
        for (int u = tid; u < 512; u += 256) dst[u] = src[u];
    }
    const int rid = selLog[30 * 32 + b];
    const float* hsrc = (rid < 32) ? nodes + ((size_t)b * 63 + rid) * 512
                                   : hF32 + (((size_t)x * 128 + rid) * 4 + b4) * 512;
    const float* csrc = (rid < 32) ? cst + ((size_t)rid * NB + b) * 512
                                   : cF32 + (((size_t)x * 128 + rid) * 4 + b4) * 512;
    for (int u = tid; u < 512; u += 256) {
        out[b * 512 + u] = hsrc[u];
        out[BH + b * 512 + u] = csrc[u];
    }
}

extern "C" void kernel_launch(void* const* d_in, const int* in_sizes, int n_in,
                              void* d_out, int out_size, void* d_ws, size_t ws_size,
                              hipStream_t stream) {
    const float* inp    = (const float*)d_in[0];
    const int*   length = (const int*)d_in[1];
    const float* W_word = (const float*)d_in[2];
    const float* b_word = (const float*)d_in[3];
    const float* W_comp = (const float*)d_in[4];
    const float* b_comp = (const float*)d_in[5];
    const float* q      = (const float*)d_in[6];
    float* out = (float*)d_out;
    float* ws  = (float*)d_ws;

    _Float16*  Wth  = (_Float16*)(ws + OFF_WTH);
    _Float16*  Wtl  = (_Float16*)(ws + OFF_WTL);
    _Float16*  WpH  = (_Float16*)(ws + OFF_WPH);
    _Float16*  WpL  = (_Float16*)(ws + OFF_WPL);
    _Float16*  hTH  = (_Float16*)(ws + OFF_HTH);
    _Float16*  hTL  = (_Float16*)(ws + OFF_HTL);
    float*     hF32 = ws + OFF_HF32;
    float*     cF32 = ws + OFF_CF32;
    float*     cst  = ws + OFF_CST;
    float*     lpart= ws + OFF_LPART;
    int*       selLog = (int*)(ws + OFF_SEL);
    int*       ireg   = (int*)(ws + OFF_IREG);

    init_kernel<<<2, 256, 0, stream>>>(ireg, hTH, hTL);
    wsplit_kernel<<<dim3(NC5 / 32, 1024 / 32), 256, 0, stream>>>(W_comp, Wth, Wtl);
    wperm_kernel<<<32, 256, 0, stream>>>(Wth, Wtl, WpH, WpL);
    word_gemm64<<<dim3(16, 16), 256, 0, stream>>>(inp, W_word, b_word,
                                                  hTH, hTL, cst, out);
    tree_loop<<<256, 256, 0, stream>>>(hTH, hTL, hF32, cF32, WpH, WpL, b_comp, q,
                                       length, cst, lpart, selLog, ireg);
    gather_kernel<<<NB, 256, 0, stream>>>(hF32, cF32, cst, selLog, out);
}